// Round 1
// baseline (6712.634 us; speedup 1.0000x reference)
//
#include <hip/hip_runtime.h>

#define TPB 256

// ---------------- degree / norm ----------------
__global__ __launch_bounds__(TPB) void k_deg_count(const int* __restrict__ dst,
                                                   float* __restrict__ deg, int E) {
    int i = blockIdx.x * TPB + threadIdx.x;
    if (i < E) atomicAdd(&deg[dst[i]], 1.0f);
}

__global__ __launch_bounds__(TPB) void k_dinv(float* __restrict__ deg, int N) {
    int i = blockIdx.x * TPB + threadIdx.x;
    if (i < N) deg[i] = rsqrtf(deg[i] + 1.0f);  // +1 self-loop; always > 0
}

// ---------------- edge aggregation (push, atomics) ----------------
// acc[dst] += dinv[src] * h[src]   (dinv[dst] applied later in finalize)
template <int F>  // F multiple of 4
__global__ __launch_bounds__(TPB) void k_agg(const int* __restrict__ src,
                                             const int* __restrict__ dst,
                                             const float* __restrict__ dinv,
                                             const float* __restrict__ h,
                                             float* __restrict__ acc, int E) {
    constexpr int L = F / 4;  // lanes per edge
    int t = blockIdx.x * TPB + threadIdx.x;
    if (t >= E * L) return;
    int e = t / L, q = t % L;
    int s = src[e], d = dst[e];
    float w = dinv[s];
    float4 v = ((const float4*)h)[s * L + q];
    float* out = acc + d * F + q * 4;
    atomicAdd(out + 0, w * v.x);
    atomicAdd(out + 1, w * v.y);
    atomicAdd(out + 2, w * v.z);
    atomicAdd(out + 3, w * v.w);
}

// ---------------- layer 0: finalize agg8 + matmul 8->64 + bias + tanh ----------------
__global__ __launch_bounds__(TPB) void k_l0(const float* __restrict__ x,
                                            const float* __restrict__ acc8,
                                            const float* __restrict__ dinv,
                                            const float* __restrict__ W0,
                                            const float* __restrict__ b0,
                                            float* __restrict__ h0, int N) {
    int t = blockIdx.x * TPB + threadIdx.x;
    int n = t >> 6, f = t & 63;
    if (n >= N) return;
    float di = dinv[n], di2 = di * di;
    float row[8];
#pragma unroll
    for (int k = 0; k < 8; k++) row[k] = di * acc8[n * 8 + k] + di2 * x[n * 8 + k];
    float a = b0[f];
#pragma unroll
    for (int k = 0; k < 8; k++) a += row[k] * W0[k * 64 + f];
    h0[t] = tanhf(a);
}

// ---------------- layer 1: finalize agg64 + matmul 64->64 + bias + relu ----------------
__global__ __launch_bounds__(TPB) void k_l1(const float* __restrict__ h0,
                                            const float* __restrict__ acc,
                                            const float* __restrict__ dinv,
                                            const float* __restrict__ W,
                                            const float* __restrict__ b,
                                            float* __restrict__ out, int N) {
    __shared__ float Ws[64 * 64];
    __shared__ float rows[4][64];
    int tid = threadIdx.x;
    for (int i = tid; i < 64 * 64; i += TPB) Ws[i] = W[i];
    int grp = tid >> 6, f = tid & 63;
    int n = blockIdx.x * 4 + grp;
    if (n < N) {
        float di = dinv[n], di2 = di * di;
        rows[grp][f] = di * acc[n * 64 + f] + di2 * h0[n * 64 + f];
    }
    __syncthreads();
    if (n >= N) return;
    float a = b[f];
#pragma unroll 8
    for (int k = 0; k < 64; k++) a += rows[grp][k] * Ws[k * 64 + f];
    out[n * 64 + f] = fmaxf(a, 0.0f);
}

// ---------------- plain per-node matmul (no bias/act): t = h @ W ----------------
template <int FIN, int FOUT>
__global__ __launch_bounds__(TPB) void k_mm(const float* __restrict__ h,
                                            const float* __restrict__ W,
                                            float* __restrict__ out, int N) {
    constexpr int NPB = TPB / FOUT;
    __shared__ float Ws[FIN * FOUT];
    __shared__ float rows[NPB * FIN];
    int tid = threadIdx.x;
    for (int i = tid; i < FIN * FOUT; i += TPB) Ws[i] = W[i];
    int n0 = blockIdx.x * NPB;
    for (int i = tid; i < NPB * FIN; i += TPB) {
        int nn = n0 + i / FIN;
        rows[i] = (nn < N) ? h[n0 * FIN + i] : 0.0f;
    }
    __syncthreads();
    int grp = tid / FOUT, f = tid % FOUT;
    int n = n0 + grp;
    if (n >= N) return;
    float a = 0.0f;
#pragma unroll 8
    for (int k = 0; k < FIN; k++) a += rows[grp * FIN + k] * Ws[k * FOUT + f];
    out[n * FOUT + f] = a;
}

// ---------------- finalize for 32-feat layers: relu(dinv*acc + dinv^2*t + b) ----------------
__global__ __launch_bounds__(TPB) void k_fin32(const float* __restrict__ tbuf,
                                               const float* __restrict__ acc,
                                               const float* __restrict__ dinv,
                                               const float* __restrict__ b,
                                               float* __restrict__ out, int N) {
    int t = blockIdx.x * TPB + threadIdx.x;
    if (t >= N * 32) return;
    int n = t >> 5, k = t & 31;
    float di = dinv[n];
    float v = di * acc[t] + di * di * tbuf[t] + b[k];
    out[t] = fmaxf(v, 0.0f);
}

// ---------------- pooling: segment max (bits trick, vals>=0) + sum + count ----------------
__global__ __launch_bounds__(TPB) void k_pool(const float* __restrict__ h,
                                              const int* __restrict__ batch,
                                              float* __restrict__ gmax,
                                              float* __restrict__ gsum,
                                              float* __restrict__ cnt, int N) {
    int t = blockIdx.x * TPB + threadIdx.x;
    if (t >= N * 32) return;
    int n = t >> 5, f = t & 31;
    int g = batch[n];
    float v = h[t];
    atomicMax((unsigned int*)&gmax[g * 32 + f], __float_as_uint(v));
    atomicAdd(&gsum[g * 32 + f], v);
    if (f == 0) atomicAdd(&cnt[g], 1.0f);
}

// ---------------- output head: [gmax || gmean] @ Wout + bout ----------------
__global__ __launch_bounds__(TPB) void k_out(const float* __restrict__ gmax,
                                             const float* __restrict__ gsum,
                                             const float* __restrict__ cnt,
                                             const float* __restrict__ Wout,
                                             const float* __restrict__ bout,
                                             float* __restrict__ out, int G) {
    int t = blockIdx.x * TPB + threadIdx.x;
    if (t >= G * 10) return;
    int g = t / 10, j = t % 10;
    float c = fmaxf(cnt[g], 1.0f);
    float inv = 1.0f / c;
    float a = bout[j];
#pragma unroll
    for (int k = 0; k < 32; k++) a += gmax[g * 32 + k] * Wout[k * 10 + j];
#pragma unroll
    for (int k = 0; k < 32; k++) a += (gsum[g * 32 + k] * inv) * Wout[(32 + k) * 10 + j];
    out[t] = a;
}

static inline int cdiv(long long a, int b) { return (int)((a + b - 1) / b); }

extern "C" void kernel_launch(void* const* d_in, const int* in_sizes, int n_in,
                              void* d_out, int out_size, void* d_ws, size_t ws_size,
                              hipStream_t stream) {
    const float* x    = (const float*)d_in[0];
    const int*   ei   = (const int*)d_in[1];
    const int*   bidx = (const int*)d_in[2];
    const float* W0 = (const float*)d_in[3];
    const float* b0 = (const float*)d_in[4];
    const float* W1 = (const float*)d_in[5];
    const float* b1 = (const float*)d_in[6];
    const float* W2 = (const float*)d_in[7];
    const float* b2 = (const float*)d_in[8];
    const float* W3 = (const float*)d_in[9];
    const float* b3 = (const float*)d_in[10];
    const float* Wout = (const float*)d_in[11];
    const float* bout = (const float*)d_in[12];
    float* out = (float*)d_out;

    const int N = in_sizes[0] / 8;
    const int E = in_sizes[1] / 2;
    const int G = out_size / 10;
    const int* src = ei;
    const int* dst = ei + E;

    // workspace layout (floats)
    float* ws   = (float*)d_ws;
    float* dinv = ws;                   // N
    float* gmax = dinv + N;             // G*32
    float* gsum = gmax + G * 32;        // G*32
    float* cnt  = gsum + G * 32;        // G
    float* bufA = cnt + G;              // N*64
    float* bufB = bufA + (size_t)N * 64;  // N*64

    // --- degrees -> dinv ---
    hipMemsetAsync(dinv, 0, (size_t)N * 4, stream);
    k_deg_count<<<cdiv(E, TPB), TPB, 0, stream>>>(dst, dinv, E);
    k_dinv<<<cdiv(N, TPB), TPB, 0, stream>>>(dinv, N);

    // --- layer 0: agg8(x) -> matmul 8->64 + tanh -> h0 (bufA) ---
    hipMemsetAsync(bufB, 0, (size_t)N * 8 * 4, stream);
    k_agg<8><<<cdiv((long long)E * 2, TPB), TPB, 0, stream>>>(src, dst, dinv, x, bufB, E);
    k_l0<<<cdiv((long long)N * 64, TPB), TPB, 0, stream>>>(x, bufB, dinv, W0, b0, bufA, N);

    // --- layer 1: agg64(h0) -> matmul 64->64 + relu -> h1 (bufA in-place) ---
    hipMemsetAsync(bufB, 0, (size_t)N * 64 * 4, stream);
    k_agg<64><<<cdiv((long long)E * 16, TPB), TPB, 0, stream>>>(src, dst, dinv, bufA, bufB, E);
    k_l1<<<cdiv(N, 4), TPB, 0, stream>>>(bufA, bufB, dinv, W1, b1, bufA, N);

    // --- layer 2: t2 = h1 @ W2 (64->32); agg32(t2); finalize -> h2 (bufA) ---
    k_mm<64, 32><<<cdiv(N, 8), TPB, 0, stream>>>(bufA, W2, bufB, N);
    hipMemsetAsync(bufB + (size_t)N * 32, 0, (size_t)N * 32 * 4, stream);
    k_agg<32><<<cdiv((long long)E * 8, TPB), TPB, 0, stream>>>(src, dst, dinv, bufB,
                                                               bufB + (size_t)N * 32, E);
    k_fin32<<<cdiv((long long)N * 32, TPB), TPB, 0, stream>>>(bufB, bufB + (size_t)N * 32,
                                                              dinv, b2, bufA, N);

    // --- layer 3: t3 = h2 @ W3 (32->32); agg32(t3); finalize -> h3 (bufA) ---
    k_mm<32, 32><<<cdiv(N, 8), TPB, 0, stream>>>(bufA, W3, bufB, N);
    hipMemsetAsync(bufB + (size_t)N * 32, 0, (size_t)N * 32 * 4, stream);
    k_agg<32><<<cdiv((long long)E * 8, TPB), TPB, 0, stream>>>(src, dst, dinv, bufB,
                                                               bufB + (size_t)N * 32, E);
    k_fin32<<<cdiv((long long)N * 32, TPB), TPB, 0, stream>>>(bufB, bufB + (size_t)N * 32,
                                                              dinv, b3, bufA, N);

    // --- pooling + head ---
    hipMemsetAsync(gmax, 0, (size_t)(G * 32 * 2 + G) * 4, stream);
    k_pool<<<cdiv((long long)N * 32, TPB), TPB, 0, stream>>>(bufA, bidx, gmax, gsum, cnt, N);
    k_out<<<cdiv((long long)G * 10, TPB), TPB, 0, stream>>>(gmax, gsum, cnt, Wout, bout, out, G);
}

// Round 2
// 1508.511 us; speedup vs baseline: 4.4498x; 4.4498x over previous
//
#include <hip/hip_runtime.h>

#define TPB 256

// ---------------- degree histogram (int) ----------------
__global__ __launch_bounds__(TPB) void k_deg_count(const int* __restrict__ dst,
                                                   int* __restrict__ deg, int E) {
    int i = blockIdx.x * TPB + threadIdx.x;
    if (i < E) atomicAdd(&deg[dst[i]], 1);
}

__global__ __launch_bounds__(TPB) void k_dinv(const int* __restrict__ deg,
                                              float* __restrict__ dinv, int N) {
    int i = blockIdx.x * TPB + threadIdx.x;
    if (i < N) dinv[i] = rsqrtf((float)deg[i] + 1.0f);  // +1 self-loop
}

// ---------------- exclusive scan (3-kernel) ----------------
__global__ __launch_bounds__(TPB) void k_scan1(const int* __restrict__ deg,
                                               int* __restrict__ row_start,
                                               int* __restrict__ bsum, int N) {
    __shared__ int s[TPB];
    int tid = threadIdx.x;
    int i = blockIdx.x * TPB + tid;
    int v = (i < N) ? deg[i] : 0;
    s[tid] = v;
    __syncthreads();
    for (int off = 1; off < TPB; off <<= 1) {
        int t = (tid >= off) ? s[tid - off] : 0;
        __syncthreads();
        s[tid] += t;
        __syncthreads();
    }
    if (i < N) row_start[i] = s[tid] - v;  // exclusive
    if (tid == TPB - 1) bsum[blockIdx.x] = s[tid];
}

__global__ void k_scan2(int* __restrict__ bsum, int nb) {
    __shared__ int s[1024];
    int tid = threadIdx.x;
    int v = (tid < nb) ? bsum[tid] : 0;
    s[tid] = v;
    __syncthreads();
    for (int off = 1; off < 1024; off <<= 1) {
        int t = (tid >= off) ? s[tid - off] : 0;
        __syncthreads();
        s[tid] += t;
        __syncthreads();
    }
    if (tid < nb) bsum[tid] = s[tid] - v;  // exclusive
}

__global__ __launch_bounds__(TPB) void k_scan3(int* __restrict__ row_start,
                                               const int* __restrict__ bsum, int N) {
    int i = blockIdx.x * TPB + threadIdx.x;
    if (i < N) row_start[i] += bsum[blockIdx.x];
}

__global__ __launch_bounds__(TPB) void k_copy_i(const int* __restrict__ a,
                                                int* __restrict__ b, int N) {
    int i = blockIdx.x * TPB + threadIdx.x;
    if (i < N) b[i] = a[i];
}

// ---------------- CSR scatter (counting sort by dst) ----------------
__global__ __launch_bounds__(TPB) void k_scatter(const int* __restrict__ src,
                                                 const int* __restrict__ dst,
                                                 int* __restrict__ cursor,
                                                 int* __restrict__ csr, int E) {
    int e = blockIdx.x * TPB + threadIdx.x;
    if (e >= E) return;
    int d = dst[e];
    int p = atomicAdd(&cursor[d], 1);
    csr[p] = src[e];
}

// ---------------- pull aggregation: acc[n] = sum_{s in in(n)} dinv[s]*h[s] ----------------
template <int F>  // power of 2; F threads cooperate per node
__global__ __launch_bounds__(TPB) void k_pull(const int* __restrict__ row_start,
                                              const int* __restrict__ deg,
                                              const int* __restrict__ csr,
                                              const float* __restrict__ dinv,
                                              const float* __restrict__ h,
                                              float* __restrict__ acc, int N) {
    int t = blockIdx.x * TPB + threadIdx.x;
    int node = t / F, f = t % F;
    if (node >= N) return;
    int s0 = row_start[node], dn = deg[node];
    float a = 0.0f;
    if (dn > 0) {
        int s = csr[s0];
        for (int j = 1; j < dn; j++) {
            int sn = csr[s0 + j];  // prefetch next index
            a += dinv[s] * h[(size_t)s * F + f];
            s = sn;
        }
        a += dinv[s] * h[(size_t)s * F + f];
    }
    acc[(size_t)node * F + f] = a;
}

// ---------------- layer 0: finalize agg8 + matmul 8->64 + bias + tanh ----------------
__global__ __launch_bounds__(TPB) void k_l0(const float* __restrict__ x,
                                            const float* __restrict__ acc8,
                                            const float* __restrict__ dinv,
                                            const float* __restrict__ W0,
                                            const float* __restrict__ b0,
                                            float* __restrict__ h0, int N) {
    int t = blockIdx.x * TPB + threadIdx.x;
    int n = t >> 6, f = t & 63;
    if (n >= N) return;
    float di = dinv[n], di2 = di * di;
    float row[8];
#pragma unroll
    for (int k = 0; k < 8; k++) row[k] = di * acc8[n * 8 + k] + di2 * x[n * 8 + k];
    float a = b0[f];
#pragma unroll
    for (int k = 0; k < 8; k++) a += row[k] * W0[k * 64 + f];
    h0[t] = tanhf(a);
}

// ---------------- layer 1: finalize agg64 + matmul 64->64 + bias + relu ----------------
__global__ __launch_bounds__(TPB) void k_l1(const float* __restrict__ h0,
                                            const float* __restrict__ acc,
                                            const float* __restrict__ dinv,
                                            const float* __restrict__ W,
                                            const float* __restrict__ b,
                                            float* __restrict__ out, int N) {
    __shared__ float Ws[64 * 64];
    __shared__ float rows[4][64];
    int tid = threadIdx.x;
    for (int i = tid; i < 64 * 64; i += TPB) Ws[i] = W[i];
    int grp = tid >> 6, f = tid & 63;
    int n = blockIdx.x * 4 + grp;
    if (n < N) {
        float di = dinv[n], di2 = di * di;
        rows[grp][f] = di * acc[(size_t)n * 64 + f] + di2 * h0[(size_t)n * 64 + f];
    }
    __syncthreads();
    if (n >= N) return;
    float a = b[f];
#pragma unroll 8
    for (int k = 0; k < 64; k++) a += rows[grp][k] * Ws[k * 64 + f];
    out[(size_t)n * 64 + f] = fmaxf(a, 0.0f);
}

// ---------------- plain per-node matmul: t = h @ W ----------------
template <int FIN, int FOUT>
__global__ __launch_bounds__(TPB) void k_mm(const float* __restrict__ h,
                                            const float* __restrict__ W,
                                            float* __restrict__ out, int N) {
    constexpr int NPB = TPB / FOUT;
    __shared__ float Ws[FIN * FOUT];
    __shared__ float rows[NPB * FIN];
    int tid = threadIdx.x;
    for (int i = tid; i < FIN * FOUT; i += TPB) Ws[i] = W[i];
    int n0 = blockIdx.x * NPB;
    for (int i = tid; i < NPB * FIN; i += TPB) {
        int nn = n0 + i / FIN;
        rows[i] = (nn < N) ? h[(size_t)n0 * FIN + i] : 0.0f;
    }
    __syncthreads();
    int grp = tid / FOUT, f = tid % FOUT;
    int n = n0 + grp;
    if (n >= N) return;
    float a = 0.0f;
#pragma unroll 8
    for (int k = 0; k < FIN; k++) a += rows[grp * FIN + k] * Ws[k * FOUT + f];
    out[(size_t)n * FOUT + f] = a;
}

// ---------------- finalize 32-feat layers: relu(dinv*acc + dinv^2*t + b) ----------------
__global__ __launch_bounds__(TPB) void k_fin32(const float* __restrict__ tbuf,
                                               const float* __restrict__ acc,
                                               const float* __restrict__ dinv,
                                               const float* __restrict__ b,
                                               float* __restrict__ out, int N) {
    int t = blockIdx.x * TPB + threadIdx.x;
    if (t >= N * 32) return;
    int n = t >> 5, k = t & 31;
    float di = dinv[n];
    float v = di * acc[t] + di * di * tbuf[t] + b[k];
    out[t] = fmaxf(v, 0.0f);
}

// ---------------- pooling ----------------
__global__ __launch_bounds__(TPB) void k_pool(const float* __restrict__ h,
                                              const int* __restrict__ batch,
                                              float* __restrict__ gmax,
                                              float* __restrict__ gsum,
                                              float* __restrict__ cnt, int N) {
    int t = blockIdx.x * TPB + threadIdx.x;
    if (t >= N * 32) return;
    int n = t >> 5, f = t & 31;
    int g = batch[n];
    float v = h[t];
    atomicMax((unsigned int*)&gmax[g * 32 + f], __float_as_uint(v));
    atomicAdd(&gsum[g * 32 + f], v);
    if (f == 0) atomicAdd(&cnt[g], 1.0f);
}

// ---------------- head ----------------
__global__ __launch_bounds__(TPB) void k_out(const float* __restrict__ gmax,
                                             const float* __restrict__ gsum,
                                             const float* __restrict__ cnt,
                                             const float* __restrict__ Wout,
                                             const float* __restrict__ bout,
                                             float* __restrict__ out, int G) {
    int t = blockIdx.x * TPB + threadIdx.x;
    if (t >= G * 10) return;
    int g = t / 10, j = t % 10;
    float inv = 1.0f / fmaxf(cnt[g], 1.0f);
    float a = bout[j];
#pragma unroll
    for (int k = 0; k < 32; k++) a += gmax[g * 32 + k] * Wout[k * 10 + j];
#pragma unroll
    for (int k = 0; k < 32; k++) a += (gsum[g * 32 + k] * inv) * Wout[(32 + k) * 10 + j];
    out[t] = a;
}

static inline int cdiv(long long a, int b) { return (int)((a + b - 1) / b); }

extern "C" void kernel_launch(void* const* d_in, const int* in_sizes, int n_in,
                              void* d_out, int out_size, void* d_ws, size_t ws_size,
                              hipStream_t stream) {
    const float* x    = (const float*)d_in[0];
    const int*   ei   = (const int*)d_in[1];
    const int*   bidx = (const int*)d_in[2];
    const float* W0 = (const float*)d_in[3];
    const float* b0 = (const float*)d_in[4];
    const float* W1 = (const float*)d_in[5];
    const float* b1 = (const float*)d_in[6];
    const float* W2 = (const float*)d_in[7];
    const float* b2 = (const float*)d_in[8];
    const float* W3 = (const float*)d_in[9];
    const float* b3 = (const float*)d_in[10];
    const float* Wout = (const float*)d_in[11];
    const float* bout = (const float*)d_in[12];
    float* out = (float*)d_out;

    const int N = in_sizes[0] / 8;
    const int E = in_sizes[1] / 2;
    const int G = out_size / 10;
    const int* src = ei;
    const int* dst = ei + E;

    // ---- workspace layout ----
    char* w = (char*)d_ws;
    int*   deg_i     = (int*)w;    w += (size_t)N * 4;
    int*   row_start = (int*)w;    w += (size_t)N * 4;
    float* dinv      = (float*)w;  w += (size_t)N * 4;
    float* gmax      = (float*)w;  w += (size_t)G * 32 * 4;
    float* gsum      = (float*)w;  w += (size_t)G * 32 * 4;
    float* cnt       = (float*)w;  w += (size_t)G * 4;
    int*   csr       = (int*)w;    w += (size_t)E * 4;
    float* bufA      = (float*)w;  w += (size_t)N * 64 * 4;
    float* bufB      = (float*)w;  w += (size_t)N * 64 * 4;
    // cursor & bsum alias bufA: only used before any layer writes bufA
    int* cursor = (int*)bufA;
    int* bsum   = (int*)bufA + N;

    const int nb = cdiv(N, TPB);

    // ---- CSR build ----
    hipMemsetAsync(deg_i, 0, (size_t)N * 4, stream);
    k_deg_count<<<cdiv(E, TPB), TPB, 0, stream>>>(dst, deg_i, E);
    k_dinv<<<nb, TPB, 0, stream>>>(deg_i, dinv, N);
    k_scan1<<<nb, TPB, 0, stream>>>(deg_i, row_start, bsum, N);
    k_scan2<<<1, 1024, 0, stream>>>(bsum, nb);
    k_scan3<<<nb, TPB, 0, stream>>>(row_start, bsum, N);
    k_copy_i<<<nb, TPB, 0, stream>>>(row_start, cursor, N);
    k_scatter<<<cdiv(E, TPB), TPB, 0, stream>>>(src, dst, cursor, csr, E);

    // ---- layer 0: pull8(x) -> 8->64 matmul + tanh -> bufA ----
    k_pull<8><<<cdiv((long long)N * 8, TPB), TPB, 0, stream>>>(row_start, deg_i, csr, dinv, x, bufB, N);
    k_l0<<<cdiv((long long)N * 64, TPB), TPB, 0, stream>>>(x, bufB, dinv, W0, b0, bufA, N);

    // ---- layer 1: pull64(h0) -> 64->64 matmul + relu -> bufA ----
    k_pull<64><<<cdiv((long long)N * 64, TPB), TPB, 0, stream>>>(row_start, deg_i, csr, dinv, bufA, bufB, N);
    k_l1<<<cdiv(N, 4), TPB, 0, stream>>>(bufA, bufB, dinv, W1, b1, bufA, N);

    // ---- layer 2: t2 = h1@W2 ; pull32(t2) ; finalize ----
    k_mm<64, 32><<<cdiv(N, 8), TPB, 0, stream>>>(bufA, W2, bufB, N);
    k_pull<32><<<cdiv((long long)N * 32, TPB), TPB, 0, stream>>>(row_start, deg_i, csr, dinv, bufB, bufB + (size_t)N * 32, N);
    k_fin32<<<cdiv((long long)N * 32, TPB), TPB, 0, stream>>>(bufB, bufB + (size_t)N * 32, dinv, b2, bufA, N);

    // ---- layer 3: t3 = h2@W3 ; pull32(t3) ; finalize ----
    k_mm<32, 32><<<cdiv(N, 8), TPB, 0, stream>>>(bufA, W3, bufB, N);
    k_pull<32><<<cdiv((long long)N * 32, TPB), TPB, 0, stream>>>(row_start, deg_i, csr, dinv, bufB, bufB + (size_t)N * 32, N);
    k_fin32<<<cdiv((long long)N * 32, TPB), TPB, 0, stream>>>(bufB, bufB + (size_t)N * 32, dinv, b3, bufA, N);

    // ---- pooling + head ----
    hipMemsetAsync(gmax, 0, (size_t)(G * 32 * 2 + G) * 4, stream);
    k_pool<<<cdiv((long long)N * 32, TPB), TPB, 0, stream>>>(bufA, bidx, gmax, gsum, cnt, N);
    k_out<<<cdiv((long long)G * 10, TPB), TPB, 0, stream>>>(gmax, gsum, cnt, Wout, bout, out, G);
}

// Round 3
// 1226.213 us; speedup vs baseline: 5.4743x; 1.2302x over previous
//
#include <hip/hip_runtime.h>

#define TPB 256

// ---------------- degree histogram (int) ----------------
__global__ __launch_bounds__(TPB) void k_deg_count(const int* __restrict__ dst,
                                                   int* __restrict__ deg, int E) {
    int i = blockIdx.x * TPB + threadIdx.x;
    if (i < E) atomicAdd(&deg[dst[i]], 1);
}

__global__ __launch_bounds__(TPB) void k_dinv(const int* __restrict__ deg,
                                              float* __restrict__ dinv, int N) {
    int i = blockIdx.x * TPB + threadIdx.x;
    if (i < N) dinv[i] = rsqrtf((float)deg[i] + 1.0f);  // +1 self-loop
}

// ---------------- exclusive scan (3-kernel) ----------------
__global__ __launch_bounds__(TPB) void k_scan1(const int* __restrict__ deg,
                                               int* __restrict__ row_start,
                                               int* __restrict__ bsum, int N) {
    __shared__ int s[TPB];
    int tid = threadIdx.x;
    int i = blockIdx.x * TPB + tid;
    int v = (i < N) ? deg[i] : 0;
    s[tid] = v;
    __syncthreads();
    for (int off = 1; off < TPB; off <<= 1) {
        int t = (tid >= off) ? s[tid - off] : 0;
        __syncthreads();
        s[tid] += t;
        __syncthreads();
    }
    if (i < N) row_start[i] = s[tid] - v;  // exclusive
    if (tid == TPB - 1) bsum[blockIdx.x] = s[tid];
}

__global__ void k_scan2(int* __restrict__ bsum, int nb) {
    __shared__ int s[1024];
    int tid = threadIdx.x;
    int v = (tid < nb) ? bsum[tid] : 0;
    s[tid] = v;
    __syncthreads();
    for (int off = 1; off < 1024; off <<= 1) {
        int t = (tid >= off) ? s[tid - off] : 0;
        __syncthreads();
        s[tid] += t;
        __syncthreads();
    }
    if (tid < nb) bsum[tid] = s[tid] - v;  // exclusive
}

__global__ __launch_bounds__(TPB) void k_scan3(int* __restrict__ row_start,
                                               const int* __restrict__ bsum,
                                               int* __restrict__ cursor, int N) {
    int i = blockIdx.x * TPB + threadIdx.x;
    if (i < N) {
        int v = row_start[i] + bsum[blockIdx.x];
        row_start[i] = v;
        cursor[i] = v;
    }
}

// ---------------- CSR scatter (counting sort by dst) ----------------
__global__ __launch_bounds__(TPB) void k_scatter(const int* __restrict__ src,
                                                 const int* __restrict__ dst,
                                                 int* __restrict__ cursor,
                                                 int* __restrict__ csr, int E) {
    int e = blockIdx.x * TPB + threadIdx.x;
    if (e >= E) return;
    int d = dst[e];
    int p = atomicAdd(&cursor[d], 1);
    csr[p] = src[e];
}

// ---------------- pull aggregation: acc[n] = sum_{s in in(n)} dinv[s]*h[s] ----------------
// One wave per node. Lane = (edge_group, feature_quad). float4 loads; shfl_xor
// cross-edge-group reduction.
template <int F>  // F in {8, 32, 64}
__global__ __launch_bounds__(TPB) void k_pull(const int* __restrict__ row_start,
                                              const int* __restrict__ deg,
                                              const int* __restrict__ csr,
                                              const float* __restrict__ dinv,
                                              const float* __restrict__ h,
                                              float* __restrict__ acc, int N) {
    constexpr int Q = F / 4;    // float4 quads per node
    constexpr int EG = 64 / Q;  // parallel edge groups per wave
    int wave = (blockIdx.x * TPB + threadIdx.x) >> 6;
    int lane = threadIdx.x & 63;
    if (wave >= N) return;
    int q = lane % Q, eg = lane / Q;
    int s0 = row_start[wave], dn = deg[wave];
    const float4* h4 = (const float4*)h;
    float4 a = {0.f, 0.f, 0.f, 0.f};
    for (int j = eg; j < dn; j += EG) {
        int s = csr[s0 + j];
        float w = dinv[s];
        float4 v = h4[(size_t)s * Q + q];
        a.x += w * v.x;
        a.y += w * v.y;
        a.z += w * v.z;
        a.w += w * v.w;
    }
#pragma unroll
    for (int off = Q; off < 64; off <<= 1) {
        a.x += __shfl_xor(a.x, off, 64);
        a.y += __shfl_xor(a.y, off, 64);
        a.z += __shfl_xor(a.z, off, 64);
        a.w += __shfl_xor(a.w, off, 64);
    }
    if (eg == 0) ((float4*)acc)[(size_t)wave * Q + q] = a;
}

// ---------------- layer 0: finalize agg8 + matmul 8->64 + bias + tanh ----------------
__global__ __launch_bounds__(TPB) void k_l0(const float* __restrict__ x,
                                            const float* __restrict__ acc8,
                                            const float* __restrict__ dinv,
                                            const float* __restrict__ W0,
                                            const float* __restrict__ b0,
                                            float* __restrict__ h0, int N) {
    int t = blockIdx.x * TPB + threadIdx.x;
    int n = t >> 6, f = t & 63;
    if (n >= N) return;
    float di = dinv[n], di2 = di * di;
    float row[8];
#pragma unroll
    for (int k = 0; k < 8; k++) row[k] = di * acc8[n * 8 + k] + di2 * x[n * 8 + k];
    float a = b0[f];
#pragma unroll
    for (int k = 0; k < 8; k++) a += row[k] * W0[k * 64 + f];
    h0[t] = tanhf(a);
}

// ---------------- layer 1: finalize agg64 + matmul 64->64 + bias + relu ----------------
__global__ __launch_bounds__(TPB) void k_l1(const float* __restrict__ h0,
                                            const float* __restrict__ acc,
                                            const float* __restrict__ dinv,
                                            const float* __restrict__ W,
                                            const float* __restrict__ b,
                                            float* __restrict__ out, int N) {
    __shared__ float Ws[64 * 64];
    __shared__ float rows[4][64];
    int tid = threadIdx.x;
    for (int i = tid; i < 64 * 64; i += TPB) Ws[i] = W[i];
    int grp = tid >> 6, f = tid & 63;
    int n = blockIdx.x * 4 + grp;
    if (n < N) {
        float di = dinv[n], di2 = di * di;
        rows[grp][f] = di * acc[(size_t)n * 64 + f] + di2 * h0[(size_t)n * 64 + f];
    }
    __syncthreads();
    if (n >= N) return;
    float a = b[f];
#pragma unroll 8
    for (int k = 0; k < 64; k++) a += rows[grp][k] * Ws[k * 64 + f];
    out[(size_t)n * 64 + f] = fmaxf(a, 0.0f);
}

// ---------------- plain per-node matmul: t = h @ W ----------------
template <int FIN, int FOUT>
__global__ __launch_bounds__(TPB) void k_mm(const float* __restrict__ h,
                                            const float* __restrict__ W,
                                            float* __restrict__ out, int N) {
    constexpr int NPB = TPB / FOUT;
    __shared__ float Ws[FIN * FOUT];
    __shared__ float rows[NPB * FIN];
    int tid = threadIdx.x;
    for (int i = tid; i < FIN * FOUT; i += TPB) Ws[i] = W[i];
    int n0 = blockIdx.x * NPB;
    for (int i = tid; i < NPB * FIN; i += TPB) {
        int nn = n0 + i / FIN;
        rows[i] = (nn < N) ? h[(size_t)n0 * FIN + i] : 0.0f;
    }
    __syncthreads();
    int grp = tid / FOUT, f = tid % FOUT;
    int n = n0 + grp;
    if (n >= N) return;
    float a = 0.0f;
#pragma unroll 8
    for (int k = 0; k < FIN; k++) a += rows[grp * FIN + k] * Ws[k * FOUT + f];
    out[(size_t)n * FOUT + f] = a;
}

// ---------------- finalize 32-feat layers: relu(dinv*acc + dinv^2*t + b) ----------------
__global__ __launch_bounds__(TPB) void k_fin32(const float* __restrict__ tbuf,
                                               const float* __restrict__ acc,
                                               const float* __restrict__ dinv,
                                               const float* __restrict__ b,
                                               float* __restrict__ out, int N) {
    int t = blockIdx.x * TPB + threadIdx.x;
    if (t >= N * 32) return;
    int n = t >> 5, k = t & 31;
    float di = dinv[n];
    float v = di * acc[t] + di * di * tbuf[t] + b[k];
    out[t] = fmaxf(v, 0.0f);
}

// ---------------- graph boundaries (batch_index is sorted) ----------------
__global__ __launch_bounds__(TPB) void k_gbound(const int* __restrict__ batch,
                                                int* __restrict__ start, int N, int G) {
    int g = blockIdx.x * TPB + threadIdx.x;
    if (g > G) return;
    int lo = 0, hi = N;
    while (lo < hi) {
        int mid = (lo + hi) >> 1;
        if (batch[mid] < g) lo = mid + 1;
        else hi = mid;
    }
    start[g] = lo;
}

// ---------------- pooling: one block per graph, no atomics ----------------
__global__ __launch_bounds__(TPB) void k_pool2(const float* __restrict__ h,
                                               const int* __restrict__ start,
                                               float* __restrict__ gmax,
                                               float* __restrict__ gsum, int G) {
    __shared__ float smax[8][32];
    __shared__ float ssum[8][32];
    int g = blockIdx.x;
    int s = start[g], e = start[g + 1];
    int tid = threadIdx.x;
    int nl = tid >> 5, f = tid & 31;
    float mx = 0.0f, sm = 0.0f;  // relu output >= 0
    for (int n = s + nl; n < e; n += 8) {
        float v = h[(size_t)n * 32 + f];
        mx = fmaxf(mx, v);
        sm += v;
    }
    smax[nl][f] = mx;
    ssum[nl][f] = sm;
    __syncthreads();
    if (nl == 0) {
#pragma unroll
        for (int k = 1; k < 8; k++) {
            mx = fmaxf(mx, smax[k][f]);
            sm += ssum[k][f];
        }
        gmax[g * 32 + f] = mx;
        gsum[g * 32 + f] = sm;
    }
}

// ---------------- head ----------------
__global__ __launch_bounds__(TPB) void k_out(const float* __restrict__ gmax,
                                             const float* __restrict__ gsum,
                                             const int* __restrict__ start,
                                             const float* __restrict__ Wout,
                                             const float* __restrict__ bout,
                                             float* __restrict__ out, int G) {
    int t = blockIdx.x * TPB + threadIdx.x;
    if (t >= G * 10) return;
    int g = t / 10, j = t % 10;
    float c = (float)(start[g + 1] - start[g]);
    float inv = 1.0f / fmaxf(c, 1.0f);
    float a = bout[j];
#pragma unroll
    for (int k = 0; k < 32; k++) a += gmax[g * 32 + k] * Wout[k * 10 + j];
#pragma unroll
    for (int k = 0; k < 32; k++) a += (gsum[g * 32 + k] * inv) * Wout[(32 + k) * 10 + j];
    out[t] = a;
}

static inline int cdiv(long long a, int b) { return (int)((a + b - 1) / b); }

extern "C" void kernel_launch(void* const* d_in, const int* in_sizes, int n_in,
                              void* d_out, int out_size, void* d_ws, size_t ws_size,
                              hipStream_t stream) {
    const float* x    = (const float*)d_in[0];
    const int*   ei   = (const int*)d_in[1];
    const int*   bidx = (const int*)d_in[2];
    const float* W0 = (const float*)d_in[3];
    const float* b0 = (const float*)d_in[4];
    const float* W1 = (const float*)d_in[5];
    const float* b1 = (const float*)d_in[6];
    const float* W2 = (const float*)d_in[7];
    const float* b2 = (const float*)d_in[8];
    const float* W3 = (const float*)d_in[9];
    const float* b3 = (const float*)d_in[10];
    const float* Wout = (const float*)d_in[11];
    const float* bout = (const float*)d_in[12];
    float* out = (float*)d_out;

    const int N = in_sizes[0] / 8;
    const int E = in_sizes[1] / 2;
    const int G = out_size / 10;
    const int* src = ei;
    const int* dst = ei + E;

    // ---- workspace layout (all chunks 16B-aligned for float4) ----
    char* w = (char*)d_ws;
    int*   deg_i     = (int*)w;    w += (size_t)N * 4;
    int*   row_start = (int*)w;    w += (size_t)N * 4;
    float* dinv      = (float*)w;  w += (size_t)N * 4;
    float* gmax      = (float*)w;  w += (size_t)G * 32 * 4;
    float* gsum      = (float*)w;  w += (size_t)G * 32 * 4;
    int*   gstart    = (int*)w;    w += (size_t)(G + 4) * 4;
    int*   csr       = (int*)w;    w += (size_t)E * 4;
    float* bufA      = (float*)w;  w += (size_t)N * 64 * 4;
    float* bufB      = (float*)w;  w += (size_t)N * 64 * 4;
    // cursor & bsum alias bufA: only used before any layer writes bufA
    int* cursor = (int*)bufA;
    int* bsum   = (int*)bufA + N;

    const int nb = cdiv(N, TPB);

    // ---- CSR build + graph boundaries ----
    hipMemsetAsync(deg_i, 0, (size_t)N * 4, stream);
    k_deg_count<<<cdiv(E, TPB), TPB, 0, stream>>>(dst, deg_i, E);
    k_dinv<<<nb, TPB, 0, stream>>>(deg_i, dinv, N);
    k_scan1<<<nb, TPB, 0, stream>>>(deg_i, row_start, bsum, N);
    k_scan2<<<1, 1024, 0, stream>>>(bsum, nb);
    k_scan3<<<nb, TPB, 0, stream>>>(row_start, bsum, cursor, N);
    k_scatter<<<cdiv(E, TPB), TPB, 0, stream>>>(src, dst, cursor, csr, E);
    k_gbound<<<cdiv(G + 1, TPB), TPB, 0, stream>>>(bidx, gstart, N, G);

    // ---- layer 0: pull8(x) -> 8->64 matmul + tanh -> bufA ----
    k_pull<8><<<cdiv(N, 4), TPB, 0, stream>>>(row_start, deg_i, csr, dinv, x, bufB, N);
    k_l0<<<cdiv((long long)N * 64, TPB), TPB, 0, stream>>>(x, bufB, dinv, W0, b0, bufA, N);

    // ---- layer 1: pull64(h0) -> 64->64 matmul + relu -> bufA ----
    k_pull<64><<<cdiv(N, 4), TPB, 0, stream>>>(row_start, deg_i, csr, dinv, bufA, bufB, N);
    k_l1<<<cdiv(N, 4), TPB, 0, stream>>>(bufA, bufB, dinv, W1, b1, bufA, N);

    // ---- layer 2: t2 = h1@W2 ; pull32(t2) ; finalize ----
    k_mm<64, 32><<<cdiv(N, 8), TPB, 0, stream>>>(bufA, W2, bufB, N);
    k_pull<32><<<cdiv(N, 4), TPB, 0, stream>>>(row_start, deg_i, csr, dinv, bufB, bufB + (size_t)N * 32, N);
    k_fin32<<<cdiv((long long)N * 32, TPB), TPB, 0, stream>>>(bufB, bufB + (size_t)N * 32, dinv, b2, bufA, N);

    // ---- layer 3: t3 = h2@W3 ; pull32(t3) ; finalize ----
    k_mm<32, 32><<<cdiv(N, 8), TPB, 0, stream>>>(bufA, W3, bufB, N);
    k_pull<32><<<cdiv(N, 4), TPB, 0, stream>>>(row_start, deg_i, csr, dinv, bufB, bufB + (size_t)N * 32, N);
    k_fin32<<<cdiv((long long)N * 32, TPB), TPB, 0, stream>>>(bufB, bufB + (size_t)N * 32, dinv, b3, bufA, N);

    // ---- pooling + head (no atomics) ----
    k_pool2<<<G, TPB, 0, stream>>>(bufA, gstart, gmax, gsum, G);
    k_out<<<cdiv((long long)G * 10, TPB), TPB, 0, stream>>>(gmax, gsum, gstart, Wout, bout, out, G);
}